// Round 1
// baseline (187.053 us; speedup 1.0000x reference)
//
#include <hip/hip_runtime.h>
#include <hip/hip_bf16.h>

#define NUM_TABLES 16
#define ROWS 200000
#define DIM 64
#define LOOKUPS 131072

// Each lookup row is DIM=64 floats = 16 float4s. One "slot" = one float4.
// Total slots = NUM_TABLES * LOOKUPS * 16.
__global__ void grouped_embedding_gather(const int* __restrict__ indices,
                                         const float* __restrict__ weights,
                                         float* __restrict__ out) {
    const long long total_slots = (long long)NUM_TABLES * LOOKUPS * (DIM / 4);
    const long long stride = (long long)gridDim.x * blockDim.x;
    for (long long s = (long long)blockIdx.x * blockDim.x + threadIdx.x;
         s < total_slots; s += stride) {
        const long long lookup = s >> 4;          // which (table, pos)
        const int slot = (int)(s & 15);           // float4 index within row
        const int table = (int)(lookup / LOOKUPS);
        // lookup is also the output row index (concat along dim 0)
        const int idx = indices[lookup];          // gather index into table
        const float4* __restrict__ src = reinterpret_cast<const float4*>(
            weights + (size_t)table * ((size_t)ROWS * DIM) + (size_t)idx * DIM);
        float4* __restrict__ dst = reinterpret_cast<float4*>(
            out + (size_t)lookup * DIM);
        dst[slot] = src[slot];
    }
}

extern "C" void kernel_launch(void* const* d_in, const int* in_sizes, int n_in,
                              void* d_out, int out_size, void* d_ws, size_t ws_size,
                              hipStream_t stream) {
    const int* indices = (const int*)d_in[0];
    const float* weights = (const float*)d_in[1];
    float* out = (float*)d_out;

    const int block = 256;
    const long long total_slots = (long long)NUM_TABLES * LOOKUPS * (DIM / 4);
    long long blocks_needed = (total_slots + block - 1) / block;
    int grid = (int)((blocks_needed < 2048) ? blocks_needed : 2048);

    grouped_embedding_gather<<<grid, block, 0, stream>>>(indices, weights, out);
}